// Round 1
// baseline (1495.443 us; speedup 1.0000x reference)
//
#include <hip/hip_runtime.h>
#include <stdint.h>
#include <math.h>

#define TOK   2048
#define HD    2880
#define NEXP  8
#define NPAIR 4096
#define N1    5760
#define KDIM  2880
#define BM    256
#define BN    64
#define BK    64
#define ROWCAP (NPAIR + BM)

typedef float  f32x4  __attribute__((ext_vector_type(4)));
typedef __bf16 bf16x8 __attribute__((ext_vector_type(8)));

#if defined(__has_builtin)
#if __has_builtin(__builtin_amdgcn_global_load_lds)
#define ASYNC_OK 1
#endif
#endif
#ifndef ASYNC_OK
#define ASYNC_OK 0
#endif

__device__ __forceinline__ unsigned short f2bf(float f) {
  union { float f; uint32_t u; } v; v.f = f;
  return (unsigned short)((v.u + 0x7FFFu + ((v.u >> 16) & 1u)) >> 16);
}
__device__ __forceinline__ float bf2f(unsigned int s) {
  union { uint32_t u; float f; } v; v.u = (s & 0xFFFFu) << 16;
  return v.f;
}

__device__ __forceinline__ void stage16(void* lds_base, const void* g, int lane) {
#if ASYNC_OK
  __builtin_amdgcn_global_load_lds((const __attribute__((address_space(1))) void*)g,
                                   (__attribute__((address_space(3))) void*)lds_base,
                                   16, 0, 0);
#else
  *(float4*)((char*)lds_base + lane * 16) = *(const float4*)g;
#endif
}

// ---------------- kernel 0: zero counts + cursors ----------------
__global__ void k_init(int* meta) {
  if (threadIdx.x < 16) meta[threadIdx.x] = 0;
}

// ---------------- kernel 1: router ----------------
__global__ __launch_bounds__(256) void k_router(
    const float* __restrict__ x, const float* __restrict__ rw,
    const float* __restrict__ rb, int* __restrict__ meta,
    int* __restrict__ topk_i, float* __restrict__ topk_w) {
  int t = blockIdx.x;
  int tid = threadIdx.x;
  const float* xr = x + (size_t)t * HD;
  float part[NEXP];
  #pragma unroll
  for (int e = 0; e < NEXP; e++) part[e] = 0.f;
  for (int i = tid; i < HD; i += 256) {
    float xv = xr[i];
    const float* w = rw + (size_t)i * NEXP;
    #pragma unroll
    for (int e = 0; e < NEXP; e++) part[e] += xv * w[e];
  }
  #pragma unroll
  for (int e = 0; e < NEXP; e++)
    for (int o = 32; o > 0; o >>= 1) part[e] += __shfl_down(part[e], o, 64);
  __shared__ float sred[4][NEXP];
  int wave = tid >> 6, lane = tid & 63;
  if (lane == 0)
    for (int e = 0; e < NEXP; e++) sred[wave][e] = part[e];
  __syncthreads();
  if (tid == 0) {
    float l[NEXP];
    for (int e = 0; e < NEXP; e++)
      l[e] = rb[e] + sred[0][e] + sred[1][e] + sred[2][e] + sred[3][e];
    int e0 = 0;
    for (int e = 1; e < NEXP; e++) if (l[e] > l[e0]) e0 = e;
    int e1 = -1;
    for (int e = 0; e < NEXP; e++) {
      if (e == e0) continue;
      if (e1 < 0 || l[e] > l[e1]) e1 = e;
    }
    float w0 = 1.f / (1.f + expf(l[e1] - l[e0]));
    topk_i[2 * t] = e0; topk_i[2 * t + 1] = e1;
    topk_w[2 * t] = w0; topk_w[2 * t + 1] = 1.f - w0;
    atomicAdd(&meta[e0], 1); atomicAdd(&meta[e1], 1);
  }
}

// ---------------- kernel 2: scan ----------------
__global__ void k_scan(int* meta) {
  if (threadIdx.x == 0) {
    int off = 0, toff = 0;
    meta[16] = 0; meta[32] = 0;
    for (int e = 0; e < NEXP; e++) {
      int c = meta[e];
      off += c;                 meta[16 + e + 1] = off;
      toff += (c + BM - 1) / BM; meta[32 + e + 1] = toff;
    }
  }
}

// ---------------- kernel 3: dispatch + gather x -> bf16 ----------------
__global__ __launch_bounds__(256) void k_gather(
    const float* __restrict__ x, const int* __restrict__ topk_i,
    int* __restrict__ meta, int* __restrict__ pair_pos,
    unsigned short* __restrict__ A) {
  int p = blockIdx.x;
  __shared__ int spos;
  if (threadIdx.x == 0) {
    int e = topk_i[p];
    int pos = meta[16 + e] + atomicAdd(&meta[8 + e], 1);
    pair_pos[p] = pos; spos = pos;
  }
  __syncthreads();
  int pos = spos;
  int t = p >> 1;
  const float4* xr = (const float4*)(x + (size_t)t * HD);
  unsigned short* dst = A + (size_t)pos * HD;
  for (int i = threadIdx.x; i < HD / 4; i += 256) {
    float4 v = xr[i];
    uint2 u;
    u.x = (uint32_t)f2bf(v.x) | ((uint32_t)f2bf(v.y) << 16);
    u.y = (uint32_t)f2bf(v.z) | ((uint32_t)f2bf(v.w) << 16);
    *(uint2*)(dst + i * 4) = u;
  }
}

// ---------------- grouped GEMM (MODE 0: gate_up + GLU -> act bf16; MODE 1: down + bias -> y bf16) ----------------
template <int MODE>
__global__ __launch_bounds__(256, 3) void k_gemm(
    const unsigned short* __restrict__ A, const float* __restrict__ B,
    const float* __restrict__ bias, const int* __restrict__ meta,
    unsigned short* __restrict__ outb) {
  constexpr int NB = (MODE == 0) ? N1 : HD;
  const int* toff = meta + 32;
  int mt = blockIdx.x;
  if (mt >= toff[NEXP]) return;
  int e = 0;
  while (mt >= toff[e + 1]) e++;
  const int* off = meta + 16;
  int row0 = off[e] + (mt - toff[e]) * BM;
  int rows_valid = off[e + 1] - row0;
  int nb0 = blockIdx.y * BN;

  __shared__ unsigned short As[BM * BK];  // [m][k] bf16, row 128B
  __shared__ unsigned short Bs[BN * BK];  // [n][k] bf16, 16B-block XOR swizzle

  int tid = threadIdx.x;
  int lane = tid & 63, wave = tid >> 6;
  int q = lane >> 4, nl = lane & 15;

  const float* Bexp = B + (size_t)e * KDIM * NB;
  bool wave_active = (wave * 64) < rows_valid;

  f32x4 acc[4][4];
  #pragma unroll
  for (int i = 0; i < 4; i++)
    #pragma unroll
    for (int j = 0; j < 4; j++) acc[i][j] = (f32x4){0.f, 0.f, 0.f, 0.f};

  const char* gA = (const char*)(A + (size_t)(row0 + wave * 64 + (lane >> 3)) * KDIM)
                   + (lane & 7) * 16;
  int bk0 = (tid >> 4) * 4;   // k row of 4x4 micro-tile
  int bn0 = (tid & 15) * 4;   // n col of 4x4 micro-tile

  for (int kt = 0; kt < KDIM / BK; kt++) {
    // ---- stage A (bf16, k-contig) via async global->LDS ----
    #pragma unroll
    for (int i = 0; i < 8; i++) {
      char* lb = (char*)As + (wave * 64 + i * 8) * (BK * 2);
      const char* g = gA + (size_t)kt * (BK * 2) + (size_t)i * 8 * (KDIM * 2);
      stage16(lb, g, lane);
    }
    // ---- stage B: fp32 coalesced load -> bf16 -> transposed swizzled LDS ----
    {
      const float* bg = Bexp + (size_t)(kt * BK + bk0) * NB + (nb0 + bn0);
      float4 rw0 = *(const float4*)(bg);
      float4 rw1 = *(const float4*)(bg + NB);
      float4 rw2 = *(const float4*)(bg + 2 * (size_t)NB);
      float4 rw3 = *(const float4*)(bg + 3 * (size_t)NB);
      float rv[4][4] = {{rw0.x, rw0.y, rw0.z, rw0.w},
                        {rw1.x, rw1.y, rw1.z, rw1.w},
                        {rw2.x, rw2.y, rw2.z, rw2.w},
                        {rw3.x, rw3.y, rw3.z, rw3.w}};
      #pragma unroll
      for (int j = 0; j < 4; j++) {
        int n = bn0 + j;
        uint2 u;
        u.x = (uint32_t)f2bf(rv[0][j]) | ((uint32_t)f2bf(rv[1][j]) << 16);
        u.y = (uint32_t)f2bf(rv[2][j]) | ((uint32_t)f2bf(rv[3][j]) << 16);
        int phys = n * (BK * 2) + (((bk0 >> 3) ^ (n & 7)) << 4) + (bk0 & 7) * 2;
        *(uint2*)((char*)Bs + phys) = u;
      }
    }
    __syncthreads();
    if (wave_active) {
      #pragma unroll
      for (int s = 0; s < 2; s++) {
        bf16x8 af[4], bfr[4];
        #pragma unroll
        for (int mi = 0; mi < 4; mi++) {
          int row = wave * 64 + mi * 16 + nl;
          af[mi] = *(const bf16x8*)((const char*)As + row * (BK * 2) + (s * 32 + q * 8) * 2);
        }
        #pragma unroll
        for (int nj = 0; nj < 4; nj++) {
          int n = nj * 16 + nl;
          int kb8 = s * 4 + q;
          bfr[nj] = *(const bf16x8*)((const char*)Bs + n * (BK * 2) + ((kb8 ^ (n & 7)) << 4));
        }
        #pragma unroll
        for (int mi = 0; mi < 4; mi++)
          #pragma unroll
          for (int nj = 0; nj < 4; nj++)
            acc[mi][nj] = __builtin_amdgcn_mfma_f32_16x16x32_bf16(af[mi], bfr[nj], acc[mi][nj], 0, 0, 0);
      }
    }
    __syncthreads();
  }

  if (!wave_active) return;
  #pragma unroll
  for (int mi = 0; mi < 4; mi++) {
    int rl = wave * 64 + mi * 16 + q * 4;
    #pragma unroll
    for (int nj = 0; nj < 4; nj++) {
      int n = nb0 + nj * 16 + nl;
      float bv = bias[(size_t)e * NB + n];
      #pragma unroll
      for (int r = 0; r < 4; r++) {
        float v = acc[mi][nj][r] + bv;
        float partner = __shfl_xor(v, 1, 64);
        if (MODE == 0) {
          if ((nl & 1) == 0 && (rl + r) < rows_valid) {
            float g = fminf(v, 7.0f);                       // gate clamp (max only)
            float u = fminf(fmaxf(partner, -7.0f), 7.0f);   // up clamp
            float glu = g / (1.0f + expf(-1.702f * g));
            outb[(size_t)(row0 + rl + r) * HD + (n >> 1)] = f2bf((u + 1.0f) * glu);
          }
        } else {
          if ((rl + r) < rows_valid)
            outb[(size_t)(row0 + rl + r) * HD + n] = f2bf(v);
        }
      }
    }
  }
}

// ---------------- kernel 6: combine ----------------
__global__ __launch_bounds__(256) void k_combine(
    const unsigned short* __restrict__ y, const int* __restrict__ pair_pos,
    const float* __restrict__ topk_w, float* __restrict__ out) {
  int t = blockIdx.x;
  int p0 = pair_pos[2 * t], p1 = pair_pos[2 * t + 1];
  float w0 = topk_w[2 * t], w1 = topk_w[2 * t + 1];
  const unsigned short* y0 = y + (size_t)p0 * HD;
  const unsigned short* y1 = y + (size_t)p1 * HD;
  float* o = out + (size_t)t * HD;
  for (int i = threadIdx.x; i < HD / 4; i += 256) {
    uint2 a = *(const uint2*)(y0 + i * 4);
    uint2 b = *(const uint2*)(y1 + i * 4);
    float4 r;
    r.x = w0 * bf2f(a.x) + w1 * bf2f(b.x);
    r.y = w0 * bf2f(a.x >> 16) + w1 * bf2f(b.x >> 16);
    r.z = w0 * bf2f(a.y) + w1 * bf2f(b.y);
    r.w = w0 * bf2f(a.y >> 16) + w1 * bf2f(b.y >> 16);
    *(float4*)(o + i * 4) = r;
  }
}

extern "C" void kernel_launch(void* const* d_in, const int* in_sizes, int n_in,
                              void* d_out, int out_size, void* d_ws, size_t ws_size,
                              hipStream_t stream) {
  const float* x   = (const float*)d_in[0];
  const float* rw  = (const float*)d_in[1];
  const float* rb  = (const float*)d_in[2];
  const float* gup = (const float*)d_in[3];
  const float* gub = (const float*)d_in[4];
  const float* dwn = (const float*)d_in[5];
  const float* dwb = (const float*)d_in[6];
  float* out = (float*)d_out;

  char* ws = (char*)d_ws;
  int* meta = (int*)ws;                         // 64 ints: counts[8] cursors[8] offsets[9] toff[9]
  int* topk_i = meta + 64;                      // 4096
  float* topk_w = (float*)(topk_i + NPAIR);     // 4096
  int* pair_pos = (int*)(topk_w + NPAIR);       // 4096
  size_t ofs = (((size_t)((char*)(pair_pos + NPAIR) - ws)) + 255) & ~(size_t)255;
  unsigned short* Abuf = (unsigned short*)(ws + ofs);
  unsigned short* act  = Abuf + (size_t)ROWCAP * HD;
  unsigned short* ybuf = act  + (size_t)ROWCAP * HD;

  k_init<<<1, 64, 0, stream>>>(meta);
  k_router<<<TOK, 256, 0, stream>>>(x, rw, rb, meta, topk_i, topk_w);
  k_scan<<<1, 64, 0, stream>>>(meta);
  k_gather<<<NPAIR, 256, 0, stream>>>(x, topk_i, meta, pair_pos, Abuf);
  k_gemm<0><<<dim3(24, N1 / BN), 256, 0, stream>>>(Abuf, gup, gub, meta, act);
  k_gemm<1><<<dim3(24, HD / BN), 256, 0, stream>>>(act, dwn, dwb, meta, ybuf);
  k_combine<<<TOK, 256, 0, stream>>>(ybuf, pair_pos, topk_w, out);
}